// Round 1
// baseline (110.552 us; speedup 1.0000x reference)
//
#include <hip/hip_runtime.h>
#include <math.h>

#define BATCH 8
#define H 256
#define W 256
#define NPIX (BATCH * H * W)
#define CT 8  // columns per block in col_edt

// K1: per-row distance-to-nearest-zero, squared.  One block per row.
__global__ void row_edt(const float* __restrict__ target, float* __restrict__ g2) {
    __shared__ float row[W];
    const int r = blockIdx.x;            // 0 .. BATCH*H-1
    const int i = threadIdx.x;           // 0 .. 255
    row[i] = target[(size_t)r * W + i];
    __syncthreads();
    const float fi = (float)i;
    float d = 1e4f;                      // INF per reference
    #pragma unroll 8
    for (int k = 0; k < W; ++k) {
        float cand = fabsf(fi - (float)k);
        d = (row[k] == 0.0f) ? fminf(d, cand) : d;
    }
    g2[(size_t)r * W + i] = d * d;
}

// K2: column lower-envelope d2[i,w] = min_k g2[k,w] + (i-k)^2, in-place,
// plus per-image running max(d2) via uint-bits atomicMax.
__global__ void col_edt(float* __restrict__ g2, unsigned int* __restrict__ dmax2bits) {
    __shared__ float col[H][CT];
    const int tilesPerImg = W / CT;
    const int b  = blockIdx.x / tilesPerImg;
    const int w0 = (blockIdx.x % tilesPerImg) * CT;
    float* base = g2 + (size_t)b * H * W + w0;

    // stage the 8 columns (256 x 8 floats) into LDS
    for (int idx = threadIdx.x; idx < H * CT; idx += blockDim.x) {
        int k = idx / CT, c = idx % CT;
        col[k][c] = base[(size_t)k * W + c];
    }
    __syncthreads();

    const int i = threadIdx.x;           // output row
    float acc[CT];
    #pragma unroll
    for (int c = 0; c < CT; ++c) acc[c] = 3.0e38f;
    for (int k = 0; k < H; ++k) {
        float dk = (float)(i - k);
        float dk2 = dk * dk;
        #pragma unroll
        for (int c = 0; c < CT; ++c)
            acc[c] = fminf(acc[c], col[k][c] + dk2);
    }

    float m = 0.0f;
    float* outp = base + (size_t)i * W;
    #pragma unroll
    for (int c = 0; c < CT; ++c) { outp[c] = acc[c]; m = fmaxf(m, acc[c]); }

    // block-reduce max, then one atomic per block
    #pragma unroll
    for (int off = 32; off > 0; off >>= 1)
        m = fmaxf(m, __shfl_down(m, off, 64));
    __shared__ float wmax[4];
    const int lane = threadIdx.x & 63, wid = threadIdx.x >> 6;
    if (lane == 0) wmax[wid] = m;
    __syncthreads();
    if (threadIdx.x == 0) {
        float mm = fmaxf(fmaxf(wmax[0], wmax[1]), fmaxf(wmax[2], wmax[3]));
        atomicMax(dmax2bits + b, __float_as_uint(mm));   // d2 >= 0 -> bit order == value order
    }
}

// K3: weight map + BCE + mean reduction into d_out[0].
__global__ void finalize_k(const float* __restrict__ pred, const float* __restrict__ target,
                           const float* __restrict__ d2, const float* __restrict__ dmax2,
                           float* __restrict__ out) {
    const int stride = gridDim.x * blockDim.x;
    float local = 0.0f;
    for (int e = blockIdx.x * blockDim.x + threadIdx.x; e < NPIX; e += stride) {
        int b = e >> 16;                              // / (H*W)
        float denom = sqrtf(dmax2[b]) + 1e-7f;        // max(dist) + eps (sqrt commutes w/ max)
        float dist = sqrtf(d2[e]);
        float wgt = 1.0f + dist / denom;              // ALPHA = 1
        float p = pred[e], t = target[e];
        float bce = fmaxf(p, 0.0f) - p * t + log1pf(expf(-fabsf(p)));
        local += wgt * bce;
    }
    #pragma unroll
    for (int off = 32; off > 0; off >>= 1)
        local += __shfl_down(local, off, 64);
    __shared__ float wsum[4];
    const int lane = threadIdx.x & 63, wid = threadIdx.x >> 6;
    if (lane == 0) wsum[wid] = local;
    __syncthreads();
    if (threadIdx.x == 0) {
        float s = wsum[0] + wsum[1] + wsum[2] + wsum[3];
        atomicAdd(out, s * (1.0f / (float)NPIX));
    }
}

extern "C" void kernel_launch(void* const* d_in, const int* in_sizes, int n_in,
                              void* d_out, int out_size, void* d_ws, size_t ws_size,
                              hipStream_t stream) {
    const float* pred   = (const float*)d_in[0];
    const float* target = (const float*)d_in[1];

    float* g2 = (float*)d_ws;                                   // NPIX floats (g2 -> d2 in place)
    unsigned int* dmax2 = (unsigned int*)((char*)d_ws + (size_t)NPIX * sizeof(float)); // 8 floats

    hipMemsetAsync(dmax2, 0, BATCH * sizeof(unsigned int), stream);
    hipMemsetAsync(d_out, 0, sizeof(float), stream);

    row_edt<<<BATCH * H, 256, 0, stream>>>(target, g2);
    col_edt<<<BATCH * (W / CT), 256, 0, stream>>>(g2, dmax2);
    finalize_k<<<512, 256, 0, stream>>>(pred, target, g2, (const float*)dmax2, (float*)d_out);
}

// Round 2
// 105.937 us; speedup vs baseline: 1.0436x; 1.0436x over previous
//
#include <hip/hip_runtime.h>
#include <math.h>

#define BATCH 8
#define H 256
#define W 256
#define NPIX (BATCH * H * W)
#define CT 4   // columns per block in col_edt_fused -> 512 blocks (2/CU)

// K1: per-row distance-to-nearest-zero, squared. One block per row.
// Block 0 also zero-inits the accumulators consumed by K2 (stream-ordered).
__global__ void row_edt(const float* __restrict__ target, float* __restrict__ g2,
                        unsigned int* __restrict__ dmax2bits, float* __restrict__ sums) {
    if (blockIdx.x == 0) {
        int t = threadIdx.x;
        if (t < BATCH) dmax2bits[t] = 0u;
        if (t < BATCH + 1) sums[t] = 0.0f;  // sums[0..7] = per-image sum(dist*bce), sums[8] = sum(bce)
    }
    __shared__ float row[W];
    const int r = blockIdx.x;            // 0 .. BATCH*H-1
    const int i = threadIdx.x;           // 0 .. 255
    row[i] = target[(size_t)r * W + i];
    __syncthreads();
    const float fi = (float)i;
    float d = 1e4f;                      // INF per reference
    #pragma unroll 8
    for (int k = 0; k < W; ++k) {
        float cand = fabsf(fi - (float)k);
        d = (row[k] == 0.0f) ? fminf(d, cand) : d;
    }
    g2[(size_t)r * W + i] = d * d;
}

__device__ __forceinline__ float bce_logits(float p, float t) {
    return fmaxf(p, 0.0f) - p * t + log1pf(expf(-fabsf(p)));
}

// K2: column lower-envelope d2[i,w] = min_k g2[k,w] + (i-k)^2, fused with the
// BCE epilogue. Accumulates per-image sum(dist*bce), global sum(bce), and
// per-image max(d2) (uint-bits atomicMax). d2 is never written to global.
__global__ void col_edt_fused(const float* __restrict__ g2,
                              const float* __restrict__ pred,
                              const float* __restrict__ target,
                              unsigned int* __restrict__ dmax2bits,
                              float* __restrict__ sums) {
    __shared__ float col[H][CT];         // 4 KB
    const int tiles = W / CT;            // 64
    const int b  = blockIdx.x / tiles;
    const int w0 = (blockIdx.x % tiles) * CT;
    const int i  = threadIdx.x;          // output row

    // stage the CT columns: thread i loads row i's 4 contiguous floats
    const float* gb = g2 + ((size_t)b * H) * W + w0;
    *(float4*)&col[i][0] = *(const float4*)(gb + (size_t)i * W);
    __syncthreads();

    float acc0 = 3.0e38f, acc1 = 3.0e38f, acc2 = 3.0e38f, acc3 = 3.0e38f;
    for (int k = 0; k < H; ++k) {
        float dk  = (float)(i - k);
        float dk2 = dk * dk;
        float4 c4 = *(const float4*)&col[k][0];   // broadcast read, conflict-free
        acc0 = fminf(acc0, c4.x + dk2);
        acc1 = fminf(acc1, c4.y + dk2);
        acc2 = fminf(acc2, c4.z + dk2);
        acc3 = fminf(acc3, c4.w + dk2);
    }

    const size_t off = ((size_t)(b * H + i)) * W + w0;
    const float4 p4 = *(const float4*)(pred + off);
    const float4 t4 = *(const float4*)(target + off);

    float m = fmaxf(fmaxf(acc0, acc1), fmaxf(acc2, acc3));  // max d2 (per thread)
    float b0 = bce_logits(p4.x, t4.x);
    float b1 = bce_logits(p4.y, t4.y);
    float b2 = bce_logits(p4.z, t4.z);
    float b3 = bce_logits(p4.w, t4.w);
    float sb  = (b0 + b1) + (b2 + b3);
    float sdb = (sqrtf(acc0) * b0 + sqrtf(acc1) * b1) + (sqrtf(acc2) * b2 + sqrtf(acc3) * b3);

    // block reduce: max m, sum sb, sum sdb
    #pragma unroll
    for (int o = 32; o > 0; o >>= 1) {
        m   = fmaxf(m, __shfl_down(m, o, 64));
        sb  += __shfl_down(sb, o, 64);
        sdb += __shfl_down(sdb, o, 64);
    }
    __shared__ float red[3][4];
    const int lane = i & 63, wid = i >> 6;
    if (lane == 0) { red[0][wid] = m; red[1][wid] = sb; red[2][wid] = sdb; }
    __syncthreads();
    if (i == 0) {
        float mm  = fmaxf(fmaxf(red[0][0], red[0][1]), fmaxf(red[0][2], red[0][3]));
        float tsb = (red[1][0] + red[1][1]) + (red[1][2] + red[1][3]);
        float tsd = (red[2][0] + red[2][1]) + (red[2][2] + red[2][3]);
        atomicMax(dmax2bits + b, __float_as_uint(mm));  // d2 >= 0: bit order == value order
        atomicAdd(sums + b, tsd);
        atomicAdd(sums + BATCH, tsb);
    }
}

// K3: tiny combine -> scalar output.
__global__ void final_k(const unsigned int* __restrict__ dmax2bits,
                        const float* __restrict__ sums, float* __restrict__ out) {
    if (threadIdx.x == 0) {
        float tot = sums[BATCH];
        #pragma unroll
        for (int b = 0; b < BATCH; ++b) {
            float dmax = sqrtf(__uint_as_float(dmax2bits[b]));
            tot += sums[b] / (dmax + 1e-7f);
        }
        out[0] = tot * (1.0f / (float)NPIX);
    }
}

extern "C" void kernel_launch(void* const* d_in, const int* in_sizes, int n_in,
                              void* d_out, int out_size, void* d_ws, size_t ws_size,
                              hipStream_t stream) {
    const float* pred   = (const float*)d_in[0];
    const float* target = (const float*)d_in[1];

    float*        g2        = (float*)d_ws;                                  // 8 MB
    unsigned int* dmax2bits = (unsigned int*)((char*)d_ws + (size_t)NPIX * sizeof(float));
    float*        sums      = (float*)(dmax2bits + BATCH);                   // 9 floats

    row_edt<<<BATCH * H, 256, 0, stream>>>(target, g2, dmax2bits, sums);
    col_edt_fused<<<BATCH * (W / CT), 256, 0, stream>>>(g2, pred, target, dmax2bits, sums);
    final_k<<<1, 64, 0, stream>>>(dmax2bits, sums, (float*)d_out);
}

// Round 3
// 84.599 us; speedup vs baseline: 1.3068x; 1.2522x over previous
//
#include <hip/hip_runtime.h>
#include <math.h>

#define BATCH 8
#define H 256
#define W 256
#define NPIX (BATCH * H * W)
#define CT 4   // columns per block in col_edt_fused -> 512 blocks (2/CU)

// K1: per-row distance-to-nearest-zero, squared — via wave ballot + bit scan.
// Block = one row. Block 0 also zero-inits accumulators consumed by K2.
__global__ void row_edt(const float* __restrict__ target, float* __restrict__ g2,
                        unsigned int* __restrict__ dmax2bits, float* __restrict__ sums) {
    if (blockIdx.x == 0 && threadIdx.x <= BATCH) {
        if (threadIdx.x < BATCH) dmax2bits[threadIdx.x] = 0u;
        sums[threadIdx.x] = 0.0f;   // sums[0..7]=per-img sum(dist*bce), sums[8]=sum(bce)
    }
    __shared__ unsigned long long masks[4];
    const int r = blockIdx.x;            // 0 .. BATCH*H-1
    const int i = threadIdx.x;           // 0 .. 255
    float t = target[(size_t)r * W + i];
    unsigned long long m = __ballot(t == 0.0f);
    if ((i & 63) == 0) masks[i >> 6] = m;
    __syncthreads();

    int best = 1 << 20;
    #pragma unroll
    for (int w = 0; w < 4; ++w) {
        unsigned long long mw = masks[w];
        int rel = i - (w << 6);          // position relative to word base
        unsigned long long mlo = (rel < 0)  ? 0ull
                               : (rel >= 63) ? mw : (mw & ((2ull << rel) - 1ull));
        unsigned long long mhi = (rel <= 0) ? mw
                               : (rel > 63)  ? 0ull : (mw & (~0ull << rel));
        if (mlo) best = min(best, rel - (63 - __builtin_clzll(mlo)));  // nearest zero at/below i
        if (mhi) best = min(best, __builtin_ctzll(mhi) - rel);         // nearest zero at/above i
    }
    float d = (best > 255) ? 1e4f : (float)best;   // INF per reference if no zero in row
    g2[(size_t)r * W + i] = d * d;
}

__device__ __forceinline__ float bce_logits(float p, float t) {
    return fmaxf(p, 0.0f) - p * t + log1pf(expf(-fabsf(p)));
}

// K2: column lower-envelope d2[i,w] = min_k g2[k,w] + (i-k)^2, fused BCE epilogue.
// Each wave handles a disjoint 64-wide k-chunk for ALL 256 output rows
// (4 per-lane row slots), partials combined through LDS. 64 LDS reads/wave
// instead of 256 -> VALU-bound at its floor.
__global__ void __launch_bounds__(256) col_edt_fused(
        const float* __restrict__ g2, const float* __restrict__ pred,
        const float* __restrict__ target, unsigned int* __restrict__ dmax2bits,
        float* __restrict__ sums) {
    __shared__ float col[H][CT];          // 4 KB
    __shared__ float part[4][H][CT];      // 16 KB
    const int tiles = W / CT;             // 64
    const int b  = blockIdx.x / tiles;
    const int w0 = (blockIdx.x % tiles) * CT;
    const int i  = threadIdx.x;           // 0..255
    const int wv = i >> 6, l = i & 63;

    // stage CT columns: thread i loads row i's 4 contiguous floats
    const float* gb = g2 + (size_t)b * H * W + w0;
    *(float4*)&col[i][0] = *(const float4*)(gb + (size_t)i * W);
    __syncthreads();

    float acc[4][CT];
    #pragma unroll
    for (int j = 0; j < 4; ++j)
        #pragma unroll
        for (int c = 0; c < CT; ++c) acc[j][c] = 3.0e38f;

    const int k0 = wv << 6;
    for (int kk = 0; kk < 64; ++kk) {
        const int k = k0 + kk;
        float4 c4 = *(const float4*)&col[k][0];    // broadcast within wave
        float d0 = (float)(l - k);
        #pragma unroll
        for (int j = 0; j < 4; ++j) {
            float dk  = d0 + (float)(64 * j);      // output row i = l + 64j
            float dk2 = dk * dk;
            acc[j][0] = fminf(acc[j][0], c4.x + dk2);
            acc[j][1] = fminf(acc[j][1], c4.y + dk2);
            acc[j][2] = fminf(acc[j][2], c4.z + dk2);
            acc[j][3] = fminf(acc[j][3], c4.w + dk2);
        }
    }
    #pragma unroll
    for (int j = 0; j < 4; ++j)
        *(float4*)&part[wv][l + 64 * j][0] = *(float4*)&acc[j][0];
    __syncthreads();

    // combine 4 wave-partials for output row i
    float4 r0 = *(const float4*)&part[0][i][0];
    float4 r1 = *(const float4*)&part[1][i][0];
    float4 r2 = *(const float4*)&part[2][i][0];
    float4 r3 = *(const float4*)&part[3][i][0];
    float dd0 = fminf(fminf(r0.x, r1.x), fminf(r2.x, r3.x));
    float dd1 = fminf(fminf(r0.y, r1.y), fminf(r2.y, r3.y));
    float dd2 = fminf(fminf(r0.z, r1.z), fminf(r2.z, r3.z));
    float dd3 = fminf(fminf(r0.w, r1.w), fminf(r2.w, r3.w));

    const size_t off = ((size_t)(b * H + i)) * W + w0;
    const float4 p4 = *(const float4*)(pred + off);
    const float4 t4 = *(const float4*)(target + off);

    float mx = fmaxf(fmaxf(dd0, dd1), fmaxf(dd2, dd3));  // per-thread max d2
    float b0 = bce_logits(p4.x, t4.x);
    float b1 = bce_logits(p4.y, t4.y);
    float b2 = bce_logits(p4.z, t4.z);
    float b3 = bce_logits(p4.w, t4.w);
    float sb  = (b0 + b1) + (b2 + b3);
    float sdb = (sqrtf(dd0) * b0 + sqrtf(dd1) * b1) + (sqrtf(dd2) * b2 + sqrtf(dd3) * b3);

    #pragma unroll
    for (int o = 32; o > 0; o >>= 1) {
        mx  = fmaxf(mx, __shfl_down(mx, o, 64));
        sb  += __shfl_down(sb, o, 64);
        sdb += __shfl_down(sdb, o, 64);
    }
    __shared__ float red[3][4];
    if (l == 0) { red[0][wv] = mx; red[1][wv] = sb; red[2][wv] = sdb; }
    __syncthreads();
    if (i == 0) {
        float mm  = fmaxf(fmaxf(red[0][0], red[0][1]), fmaxf(red[0][2], red[0][3]));
        float tsb = (red[1][0] + red[1][1]) + (red[1][2] + red[1][3]);
        float tsd = (red[2][0] + red[2][1]) + (red[2][2] + red[2][3]);
        atomicMax(dmax2bits + b, __float_as_uint(mm));   // d2>=0: bit order == value order
        atomicAdd(sums + b, tsd);
        atomicAdd(sums + BATCH, tsb);
    }
}

// K3: tiny combine -> scalar output.
__global__ void final_k(const unsigned int* __restrict__ dmax2bits,
                        const float* __restrict__ sums, float* __restrict__ out) {
    if (threadIdx.x == 0) {
        float tot = sums[BATCH];
        #pragma unroll
        for (int b = 0; b < BATCH; ++b) {
            float dmax = sqrtf(__uint_as_float(dmax2bits[b]));
            tot += sums[b] / (dmax + 1e-7f);
        }
        out[0] = tot * (1.0f / (float)NPIX);
    }
}

extern "C" void kernel_launch(void* const* d_in, const int* in_sizes, int n_in,
                              void* d_out, int out_size, void* d_ws, size_t ws_size,
                              hipStream_t stream) {
    const float* pred   = (const float*)d_in[0];
    const float* target = (const float*)d_in[1];

    float*        g2        = (float*)d_ws;                                  // 2 MB
    unsigned int* dmax2bits = (unsigned int*)((char*)d_ws + (size_t)NPIX * sizeof(float));
    float*        sums      = (float*)(dmax2bits + BATCH);                   // 9 floats

    row_edt<<<BATCH * H, 256, 0, stream>>>(target, g2, dmax2bits, sums);
    col_edt_fused<<<BATCH * (W / CT), 256, 0, stream>>>(g2, pred, target, dmax2bits, sums);
    final_k<<<1, 64, 0, stream>>>(dmax2bits, sums, (float*)d_out);
}